// Round 5
// baseline (2441.265 us; speedup 1.0000x reference)
//
#include <hip/hip_runtime.h>

#define TSTEPS 2048
#define NBATCH 512
#define H1 64
#define H2 16

__device__ __forceinline__ float fsig(float x) {
    return __builtin_amdgcn_rcpf(1.0f + __builtin_amdgcn_exp2f(-1.4426950408889634f * x));
}
__device__ __forceinline__ float ftanh(float x) {
    // tanh(x) = 1 - 2/(exp2(2x*log2e)+1); saturates correctly at +-inf
    return 1.0f - 2.0f * __builtin_amdgcn_rcpf(1.0f + __builtin_amdgcn_exp2f(2.8853900817779268f * x));
}

// DPP cross-lane add (VALU pipe, not LDS)
#define DPP_QUAD_XOR1   0xB1   // quad_perm [1,0,3,2]
#define DPP_QUAD_XOR2   0x4E   // quad_perm [2,3,0,1]
#define DPP_HALF_MIRROR 0x141  // mirror within 8-lane group
template<int CTRL>
__device__ __forceinline__ float dpp_add(float v) {
    int m = __builtin_amdgcn_mov_dpp(__float_as_int(v), CTRL, 0xF, 0xF, true);
    return v + __int_as_float(m);
}

// 8-lane all-reduce (lanes grouped by tid>>3) — verified mapping (L2 path passed r3/r4)
__device__ __forceinline__ float reduce8(float s) {
    s = dpp_add<DPP_QUAD_XOR1>(s);
    s = dpp_add<DPP_QUAD_XOR2>(s);
    s = dpp_add<DPP_HALF_MIRROR>(s);
    return s;
}

// Waves 0-7: layer 1 (512 thr, 40 weight regs/thread).
// Waves 8-9: layer 2 (128 thr, 44 weight regs/thread).
// Per-thread demand ~65 fits UNDER the RA's observed ~88-reg budget, so the
// spiller has no reason to remat weight loads into the t-loop (r3/r4 evidence:
// demand 105-145 vs budget 88 -> per-step global reloads -> 2.4-2.8 GB FETCH).
__global__ void __launch_bounds__(640, 2)
lstm2_fused(const float* __restrict__ x,      // [512, 2048, 1]
            const float* __restrict__ w_ih1,  // [256, 1]
            const float* __restrict__ w_hh1,  // [256, 64]
            const float* __restrict__ b_ih1,  // [256]
            const float* __restrict__ b_hh1,  // [256]
            const float* __restrict__ w_ih2,  // [64, 64]
            const float* __restrict__ w_hh2,  // [64, 16]
            const float* __restrict__ b_ih2,  // [64]
            const float* __restrict__ b_hh2,  // [64]
            float* __restrict__ out)          // [512, 2048, 16]
{
    const int b   = blockIdx.x;
    const int tid = threadIdx.x;

    __shared__ float x_lds[TSTEPS];
    __shared__ float h1buf[2][H1];
    __shared__ float h2buf[2][H2];

    // ---- stage x[b,:] (8 KB), zero state buffers ----
    if (tid < TSTEPS / 4) {
        const float4* xs = reinterpret_cast<const float4*>(x + (size_t)b * TSTEPS);
        reinterpret_cast<float4*>(x_lds)[tid] = xs[tid];
    }
    if (tid < 2 * H1) ((float*)h1buf)[tid] = 0.0f;
    if (tid >= 512 && tid < 512 + 2 * H2) ((float*)h2buf)[tid - 512] = 0.0f;

    // ---- Layer 1 (tid<512): channel j = tid>>3, k-octant s = tid&7 ----
    // Thread owns all 4 gate rows {j,64+j,128+j,192+j}, k-slice [s*8, s*8+8)
    const int j = tid >> 3;
    const int s8 = tid & 7;
    float w1[4][8], wx1[4], bs1[4];
    // ---- Layer 2 (tid>=512): tt = tid-512, channel m = tt>>3, octant oc = tt&7 ----
    const int tt = tid - 512;
    const int m  = tt >> 3;
    const int oc = tt & 7;
    float w2[4][8], wh2[4][2], bs2[4];

    if (tid < 512) {
        #pragma unroll
        for (int g = 0; g < 4; ++g) {
            const int r = g * H1 + j;
            const float4* w4 = reinterpret_cast<const float4*>(w_hh1 + r * H1 + s8 * 8);
            float4 v0 = w4[0], v1 = w4[1];
            w1[g][0]=v0.x; w1[g][1]=v0.y; w1[g][2]=v0.z; w1[g][3]=v0.w;
            w1[g][4]=v1.x; w1[g][5]=v1.y; w1[g][6]=v1.z; w1[g][7]=v1.w;
            wx1[g] = w_ih1[r];
            bs1[g] = b_ih1[r] + b_hh1[r];
        }
        #pragma unroll
        for (int g = 0; g < 4; ++g) {
            #pragma unroll
            for (int k = 0; k < 8; ++k) asm volatile("" : "+v"(w1[g][k]));
            asm volatile("" : "+v"(wx1[g]), "+v"(bs1[g]));
        }
    } else {
        #pragma unroll
        for (int g = 0; g < 4; ++g) {
            const int r2 = g * H2 + m;
            const float4* w4 = reinterpret_cast<const float4*>(w_ih2 + r2 * H1 + oc * 8);
            float4 v0 = w4[0], v1 = w4[1];
            w2[g][0]=v0.x; w2[g][1]=v0.y; w2[g][2]=v0.z; w2[g][3]=v0.w;
            w2[g][4]=v1.x; w2[g][5]=v1.y; w2[g][6]=v1.z; w2[g][7]=v1.w;
            float2 vh = *reinterpret_cast<const float2*>(w_hh2 + r2 * H2 + oc * 2);
            wh2[g][0] = vh.x; wh2[g][1] = vh.y;
            bs2[g] = b_ih2[r2] + b_hh2[r2];
        }
        #pragma unroll
        for (int g = 0; g < 4; ++g) {
            #pragma unroll
            for (int k = 0; k < 8; ++k) asm volatile("" : "+v"(w2[g][k]));
            asm volatile("" : "+v"(wh2[g][0]), "+v"(wh2[g][1]), "+v"(bs2[g]));
        }
    }

    float c1 = 0.0f;   // replicated across the 8 s-lanes of channel j
    float c2 = 0.0f;   // replicated across the 8 oc-lanes of channel m
    __syncthreads();

    float* outb = out + (size_t)b * TSTEPS * H2;

    // Layer 2 computes timestep t-1 while layer-1 waves compute timestep t.
    // ONE barrier per step; h1/h2 double-buffered by parity.
    for (int t = 0; t <= TSTEPS; ++t) {
        const int ri = t & 1;                  // h1buf[ri]=h1(t-1), h2buf[ri]=h2(t-2)
        const float* h1o = h1buf[ri];

        if (tid < 512) {
            // ===== Layer 1, timestep t (waves 0-7) =====
            if (t < TSTEPS) {
                const float4* h4 = reinterpret_cast<const float4*>(h1o + s8 * 8);
                float4 v0 = h4[0], v1 = h4[1];
                const float x_t = x_lds[t];
                float pre[4];
                #pragma unroll
                for (int g = 0; g < 4; ++g) {
                    float s = w1[g][0]*v0.x + w1[g][1]*v0.y + w1[g][2]*v0.z + w1[g][3]*v0.w;
                    s      += w1[g][4]*v1.x + w1[g][5]*v1.y + w1[g][6]*v1.z + w1[g][7]*v1.w;
                    pre[g] = reduce8(s) + (x_t * wx1[g] + bs1[g]);
                }
                float gi = fsig(pre[0]), gf = fsig(pre[1]), gg = ftanh(pre[2]), go = fsig(pre[3]);
                c1 = gf * c1 + gi * gg;
                float h1n = go * ftanh(c1);
                if (s8 == 0) h1buf[ri ^ 1][j] = h1n;
            }
        } else {
            // ===== Layer 2, timestep t-1 (waves 8-9) =====
            if (t >= 1) {
                const float4* h4 = reinterpret_cast<const float4*>(h1o + oc * 8);
                float4 a0 = h4[0], a1 = h4[1];
                float h2a = h2buf[ri][oc * 2], h2b = h2buf[ri][oc * 2 + 1];
                float p[4];
                #pragma unroll
                for (int g = 0; g < 4; ++g) {
                    float s = w2[g][0]*a0.x + w2[g][1]*a0.y + w2[g][2]*a0.z + w2[g][3]*a0.w;
                    s      += w2[g][4]*a1.x + w2[g][5]*a1.y + w2[g][6]*a1.z + w2[g][7]*a1.w;
                    s      += wh2[g][0]*h2a + wh2[g][1]*h2b;
                    p[g] = reduce8(s) + bs2[g];
                }
                float gi = fsig(p[0]), gf = fsig(p[1]), gg = ftanh(p[2]), go = fsig(p[3]);
                c2 = gf * c2 + gi * gg;
                float h2n = go * ftanh(c2);
                if (oc == 0) {
                    h2buf[ri ^ 1][m] = h2n;
                    outb[(size_t)(t - 1) * H2 + m] = h2n;
                }
            }
        }

        __syncthreads();   // publish h1(t) / h2(t-1) for iteration t+1
    }
}

extern "C" void kernel_launch(void* const* d_in, const int* in_sizes, int n_in,
                              void* d_out, int out_size, void* d_ws, size_t ws_size,
                              hipStream_t stream) {
    const float* x     = (const float*)d_in[0];
    const float* w_ih1 = (const float*)d_in[1];
    const float* w_hh1 = (const float*)d_in[2];
    const float* b_ih1 = (const float*)d_in[3];
    const float* b_hh1 = (const float*)d_in[4];
    const float* w_ih2 = (const float*)d_in[5];
    const float* w_hh2 = (const float*)d_in[6];
    const float* b_ih2 = (const float*)d_in[7];
    const float* b_hh2 = (const float*)d_in[8];
    float* out = (float*)d_out;

    lstm2_fused<<<NBATCH, 640, 0, stream>>>(x, w_ih1, w_hh1, b_ih1, b_hh1,
                                            w_ih2, w_hh2, b_ih2, b_hh2, out);
}

// Round 6
// 1637.884 us; speedup vs baseline: 1.4905x; 1.4905x over previous
//
#include <hip/hip_runtime.h>

#define TSTEPS 2048
#define NBATCH 512
#define H1 64
#define H2 16
#define RING 32

typedef float v2f __attribute__((ext_vector_type(2)));
typedef float v4f __attribute__((ext_vector_type(4)));

__device__ __forceinline__ float fsig(float x) {
    return __builtin_amdgcn_rcpf(1.0f + __builtin_amdgcn_exp2f(-1.4426950408889634f * x));
}
__device__ __forceinline__ float ftanh(float x) {
    // tanh(x) = 1 - 2/(exp2(2x*log2e)+1); saturates correctly at +-inf
    return 1.0f - 2.0f * __builtin_amdgcn_rcpf(1.0f + __builtin_amdgcn_exp2f(2.8853900817779268f * x));
}

// DPP cross-lane adds (VALU pipe). All controls act within 16-lane rows.
#define DPP_QUAD_XOR1   0xB1   // quad_perm [1,0,3,2]
#define DPP_QUAD_XOR2   0x4E   // quad_perm [2,3,0,1]
#define DPP_HALF_MIRROR 0x141  // mirror within 8-lane half-row
#define DPP_ROW_MIRROR  0x140  // mirror within 16-lane row
template<int CTRL>
__device__ __forceinline__ float dpp_add(float v) {
    int m = __builtin_amdgcn_mov_dpp(__float_as_int(v), CTRL, 0xF, 0xF, true);
    return v + __int_as_float(m);
}
__device__ __forceinline__ float reduce4(float s) {   // over lanes grouped by (lane&3)
    s = dpp_add<DPP_QUAD_XOR1>(s);
    s = dpp_add<DPP_QUAD_XOR2>(s);
    return s;
}
__device__ __forceinline__ float reduce16(float s) {  // over lanes grouped by (lane&15)
    s = dpp_add<DPP_QUAD_XOR1>(s);
    s = dpp_add<DPP_QUAD_XOR2>(s);
    s = dpp_add<DPP_HALF_MIRROR>(s);
    s = dpp_add<DPP_ROW_MIRROR>(s);
    return s;
}

// 4 waves, perfectly balanced: EVERY lane does its layer-1 share AND its
// layer-2 share (r5 post-mortem: unbalanced waves set the barrier pace).
// Packed fp32 (v2f) halves VALU issue for the dot products.
__global__ void __launch_bounds__(256, 2)
lstm2_fused(const float* __restrict__ x,      // [512, 2048, 1]
            const float* __restrict__ w_ih1,  // [256, 1]
            const float* __restrict__ w_hh1,  // [256, 64]
            const float* __restrict__ b_ih1,  // [256]
            const float* __restrict__ b_hh1,  // [256]
            const float* __restrict__ w_ih2,  // [64, 64]
            const float* __restrict__ w_hh2,  // [64, 16]
            const float* __restrict__ b_ih2,  // [64]
            const float* __restrict__ b_hh2,  // [64]
            float* __restrict__ out)          // [512, 2048, 16]
{
    const int b   = blockIdx.x;
    const int tid = threadIdx.x;

    __shared__ float x_lds[TSTEPS];
    __shared__ float h1buf[2][H1];
    __shared__ float h2buf[2][H2];
    __shared__ float ring[RING][H2];   // h2 output ring; flushed every 32 steps

    // ---- stage x[b,:] (8 KB), zero state buffers ----
    {
        const v4f* xs = reinterpret_cast<const v4f*>(x + (size_t)b * TSTEPS);
        v4f* xd = reinterpret_cast<v4f*>(x_lds);
        xd[tid]       = xs[tid];
        xd[tid + 256] = xs[tid + 256];
    }
    if (tid < 2 * H1) ((float*)h1buf)[tid] = 0.0f;
    if (tid < 2 * H2) ((float*)h2buf)[tid] = 0.0f;

    // ---- Layer 1 mapping: channel j = tid>>2, k-quarter q = tid&3 ----
    const int j = tid >> 2;
    const int q = tid & 3;
    v2f  w1p[4][8];            // 4 gates x 16-k slice as 8 packed pairs
    float wx1[4], bs1[4];
    #pragma unroll
    for (int g = 0; g < 4; ++g) {
        const int r = g * H1 + j;
        const v2f* ws = reinterpret_cast<const v2f*>(w_hh1 + r * H1 + q * 16);
        #pragma unroll
        for (int k = 0; k < 8; ++k) w1p[g][k] = ws[k];
        wx1[g] = w_ih1[r];
        bs1[g] = b_ih1[r] + b_hh1[r];
    }
    // ---- Layer 2 mapping: channel m = tid>>4, k-16th s16 = tid&15 ----
    // Per lane: 4 gates x (4 ih + 1 hh) weights -> 20 regs, uniform on all lanes.
    const int m   = tid >> 4;
    const int s16 = tid & 15;
    v2f  w2p[4][2];
    float wh2s[4], bs2[4];
    #pragma unroll
    for (int g = 0; g < 4; ++g) {
        const int r2 = g * H2 + m;
        const v2f* ws = reinterpret_cast<const v2f*>(w_ih2 + r2 * H1 + s16 * 4);
        w2p[g][0] = ws[0];
        w2p[g][1] = ws[1];
        wh2s[g] = w_hh2[r2 * H2 + s16];
        bs2[g]  = b_ih2[r2] + b_hh2[r2];
    }
    // keep weights register-resident (opaque defs; demand ~126 fits the 128 cap)
    #pragma unroll
    for (int g = 0; g < 4; ++g) {
        #pragma unroll
        for (int k = 0; k < 8; ++k) asm volatile("" : "+v"(w1p[g][k]));
        asm volatile("" : "+v"(w2p[g][0]), "+v"(w2p[g][1]));
        asm volatile("" : "+v"(wx1[g]), "+v"(bs1[g]), "+v"(wh2s[g]), "+v"(bs2[g]));
    }

    float c1 = 0.0f;   // replicated across the 4 q-lanes of channel j
    float c2 = 0.0f;   // replicated across the 16 s16-lanes of channel m
    __syncthreads();

    float* outb = out + (size_t)b * TSTEPS * H2;

    // Layer 2 runs one step behind layer 1; one barrier per step.
    for (int t = 0; t <= TSTEPS; ++t) {
        const int ri = t & 1;                  // h1buf[ri]=h1(t-1), h2buf[ri]=h2(t-2)
        const float* h1o = h1buf[ri];

        // ===== Layer 1, timestep t (all lanes) =====
        if (t < TSTEPS) {
            const v4f* h4 = reinterpret_cast<const v4f*>(h1o);
            v4f v0 = h4[q * 4 + 0], v1 = h4[q * 4 + 1];
            v4f v2 = h4[q * 4 + 2], v3 = h4[q * 4 + 3];
            v2f h0 = __builtin_shufflevector(v0, v0, 0, 1), h1v = __builtin_shufflevector(v0, v0, 2, 3);
            v2f h2 = __builtin_shufflevector(v1, v1, 0, 1), h3v = __builtin_shufflevector(v1, v1, 2, 3);
            v2f h4v= __builtin_shufflevector(v2, v2, 0, 1), h5v = __builtin_shufflevector(v2, v2, 2, 3);
            v2f h6 = __builtin_shufflevector(v3, v3, 0, 1), h7v = __builtin_shufflevector(v3, v3, 2, 3);
            const float x_t = x_lds[t];
            float pre[4];
            #pragma unroll
            for (int g = 0; g < 4; ++g) {
                v2f acc = w1p[g][0] * h0;      // packed fp32 mul/fma
                acc += w1p[g][1] * h1v;
                acc += w1p[g][2] * h2;
                acc += w1p[g][3] * h3v;
                acc += w1p[g][4] * h4v;
                acc += w1p[g][5] * h5v;
                acc += w1p[g][6] * h6;
                acc += w1p[g][7] * h7v;
                float s = acc.x + acc.y;
                pre[g] = reduce4(s) + (x_t * wx1[g] + bs1[g]);
            }
            float gi = fsig(pre[0]), gf = fsig(pre[1]), gg = ftanh(pre[2]), go = fsig(pre[3]);
            c1 = gf * c1 + gi * gg;
            float h1n = go * ftanh(c1);
            if (q == 0) h1buf[ri ^ 1][j] = h1n;
        }

        // ===== Layer 2, timestep t-1 (all lanes, uniform share) =====
        if (t >= 1) {
            v4f hv = reinterpret_cast<const v4f*>(h1o)[s16];
            v2f ha = __builtin_shufflevector(hv, hv, 0, 1);
            v2f hb = __builtin_shufflevector(hv, hv, 2, 3);
            const float h2p = h2buf[ri][s16];
            float p[4];
            #pragma unroll
            for (int g = 0; g < 4; ++g) {
                v2f acc = w2p[g][0] * ha;
                acc += w2p[g][1] * hb;
                float s = acc.x + acc.y + wh2s[g] * h2p;
                p[g] = reduce16(s) + bs2[g];
            }
            float gi = fsig(p[0]), gf = fsig(p[1]), gg = ftanh(p[2]), go = fsig(p[3]);
            c2 = gf * c2 + gi * gg;
            float h2n = go * ftanh(c2);
            if (s16 == 0) {
                h2buf[ri ^ 1][m] = h2n;
                ring[(t - 1) & (RING - 1)][m] = h2n;   // LDS only: no vmcnt on this step's barrier
            }
        }

        __syncthreads();

        // ---- coalesced output flush every 32 steps (vmcnt drain amortized 32x) ----
        if (t >= RING && (t & (RING - 1)) == 0) {
            const int r  = tid >> 3;       // 0..31 ring rows
            const int cp = tid & 7;        // column pair
            v2f val = *reinterpret_cast<const v2f*>(&ring[r][cp * 2]);
            *reinterpret_cast<v2f*>(outb + (size_t)(t - RING + r) * H2 + cp * 2) = val;
            __syncthreads();               // slot 0 is rewritten next step
        }
    }
}

extern "C" void kernel_launch(void* const* d_in, const int* in_sizes, int n_in,
                              void* d_out, int out_size, void* d_ws, size_t ws_size,
                              hipStream_t stream) {
    const float* x     = (const float*)d_in[0];
    const float* w_ih1 = (const float*)d_in[1];
    const float* w_hh1 = (const float*)d_in[2];
    const float* b_ih1 = (const float*)d_in[3];
    const float* b_hh1 = (const float*)d_in[4];
    const float* w_ih2 = (const float*)d_in[5];
    const float* w_hh2 = (const float*)d_in[6];
    const float* b_ih2 = (const float*)d_in[7];
    const float* b_hh2 = (const float*)d_in[8];
    float* out = (float*)d_out;

    lstm2_fused<<<NBATCH, 256, 0, stream>>>(x, w_ih1, w_hh1, b_ih1, b_hh1,
                                            w_ih2, w_hh2, b_ih2, b_hh2, out);
}